// Round 6
// baseline (995.140 us; speedup 1.0000x reference)
//
#include <hip/hip_runtime.h>
#include <math.h>

#define N 2048
#define D 128
#define R 43
#define SPLIT 8
#define CHUNKS 32   // row-chunks for column-softmax stats

typedef const __attribute__((address_space(1))) void* as1_cptr;
typedef __attribute__((address_space(3))) void* as3_ptr;

// ---------------- K0: head/tail vectors (4 lanes per row, float4) ----------------
__global__ __launch_bounds__(256) void k_headtail(
    const float* __restrict__ inputs,
    const float* __restrict__ w_head, const float* __restrict__ b_head,
    const float* __restrict__ w_tail, const float* __restrict__ b_tail,
    float* __restrict__ head, float* __restrict__ tail)
{
    const int t = threadIdx.x;
    const int row = blockIdx.x * 64 + (t >> 2);
    const int q = t & 3;                       // quarter of the row (32 floats)
    const float4* rp = (const float4*)(inputs + (size_t)row * D + q * 32);
    const float4* wh = (const float4*)(w_head + q * 32);
    const float4* wt = (const float4*)(w_tail + q * 32);
    float h = 0.f, tl = 0.f;
    #pragma unroll
    for (int k = 0; k < 8; ++k) {
        float4 v = rp[k];
        float4 a = wh[k];
        float4 b = wt[k];
        h  += v.x * a.x + v.y * a.y + v.z * a.z + v.w * a.w;
        tl += v.x * b.x + v.y * b.y + v.z * b.z + v.w * b.w;
    }
    h  += __shfl_xor(h, 1);  h  += __shfl_xor(h, 2);
    tl += __shfl_xor(tl, 1); tl += __shfl_xor(tl, 2);
    if (q == 0) {
        head[row] = h  + b_head[0];
        tail[row] = tl + b_tail[0];
    }
}

// ---------------- K1: s[i][j] = rel(i,j,:)*w + b + head[i] + tail[j] + mask ----
// Persistent double-buffered streaming (T3 minimum 2-phase):
//   STAGE(next chunk) -> compute(current chunk) -> __syncthreads()
// so the 44 KB prefetch for chunk t+1 is in flight during the entire compute
// of chunk t. grid = 256 (1 block/CU, LDS 88 KB), 64 chunks of 256 pairs each.
__global__ __launch_bounds__(256) void k_scores(
    const float* __restrict__ rel, const float* __restrict__ rel_mask,
    const float* __restrict__ w_rel, const float* __restrict__ b_rel,
    const float* __restrict__ head, const float* __restrict__ tail,
    float* __restrict__ s)
{
    __shared__ float lds[2 * 256 * R];          // 2 x 44032 B = 88064 B -> 1 block/CU
    const int t    = threadIdx.x;
    const int lane = t & 63;
    const int wave = t >> 6;
    // per-wave share of the 43 x 1KB staging instructions: 11,11,11,10
    const int k0 = wave * 11;
    const int k1 = (wave == 3) ? 43 : (k0 + 11);

    // rel-weight vector: uniform, lives in scalar regs
    float w[R];
    #pragma unroll
    for (int r = 0; r < R; ++r) w[r] = w_rel[r];
    const float brel = b_rel[0];

    char* lbase = (char*)lds;
    const int c0 = blockIdx.x * 64;             // this block's first 256-pair chunk

    // prologue: stage chunk c0 into buffer 0 (identity byte copy, 16B/lane)
    {
        const char* src = (const char*)rel + (size_t)c0 * 44032;
        for (int k = k0; k < k1; ++k)
            __builtin_amdgcn_global_load_lds(
                (as1_cptr)(src + k * 1024 + lane * 16),
                (as3_ptr)(lbase + k * 1024), 16, 0, 0);
    }

    int cur = 0;
    for (int tt = 0; tt < 64; ++tt) {
        // drain: buf[cur]'s loads complete (they streamed during the previous
        // compute phase); also fences prior reads of buf[cur^1] before overwrite
        __syncthreads();

        // issue next chunk's staging FIRST — overlaps the compute below
        if (tt < 63) {
            const char* src = (const char*)rel + (size_t)(c0 + tt + 1) * 44032;
            char* dst = lbase + (cur ^ 1) * 44032;
            for (int k = k0; k < k1; ++k)
                __builtin_amdgcn_global_load_lds(
                    (as1_cptr)(src + k * 1024 + lane * 16),
                    (as3_ptr)(dst + k * 1024), 16, 0, 0);
        }

        const size_t p = (size_t)(c0 + tt) * 256 + t;
        const int i = (int)(p >> 11);           // uniform within the chunk
        const int j = (int)(p & (N - 1));
        // issue epilogue loads early: latency hides under the 43-FMA dot
        const float hd = head[i];
        const float tl = tail[j];
        const float mk = rel_mask[p];

        // dot over R=43 from LDS; stride-43 b32 reads = 2-way bank alias (free).
        // 4 accumulators break the dependent-FMA chain (1 wave/SIMD here).
        const float* b = lds + cur * (256 * R) + t * R;
        float a0 = 0.f, a1 = 0.f, a2 = 0.f, a3 = 0.f;
        #pragma unroll
        for (int r = 0; r < 40; r += 4) {
            a0 += b[r]     * w[r];
            a1 += b[r + 1] * w[r + 1];
            a2 += b[r + 2] * w[r + 2];
            a3 += b[r + 3] * w[r + 3];
        }
        a0 += b[40] * w[40];
        a1 += b[41] * w[41];
        a2 += b[42] * w[42];

        s[p] = brel + ((a0 + a1) + (a2 + a3)) + hd + tl + mk;
        cur ^= 1;
    }
}

// ---------------- K2a: per-column partial (max, sumexp) over a 64-row chunk ----
__global__ __launch_bounds__(256) void k_colstats_part(
    const float* __restrict__ s, float* __restrict__ mpart, float* __restrict__ lpart)
{
    const int j = (blockIdx.x & 7) * 256 + threadIdx.x;   // column, coalesced
    const int c = blockIdx.x >> 3;                        // row chunk 0..31
    const int i0 = c * 64;
    float mx = -1e30f;
    for (int i = i0; i < i0 + 64; ++i)
        mx = fmaxf(mx, s[(size_t)i * N + j]);
    float sum = 0.f;
    for (int i = i0; i < i0 + 64; ++i)
        sum += __expf(s[(size_t)i * N + j] - mx);         // 2nd pass: L1/L2 hits
    mpart[c * N + j] = mx;
    lpart[c * N + j] = sum;
}

// ---------------- K2b: combine 32 chunk partials -> m, 1/l ----------------
__global__ __launch_bounds__(256) void k_colstats_comb(
    const float* __restrict__ mpart, const float* __restrict__ lpart,
    float* __restrict__ m, float* __restrict__ rl)
{
    const int j = blockIdx.x * 256 + threadIdx.x;
    float mx = -1e30f;
    #pragma unroll 8
    for (int c = 0; c < CHUNKS; ++c)
        mx = fmaxf(mx, mpart[c * N + j]);
    float sum = 0.f;
    #pragma unroll 8
    for (int c = 0; c < CHUNKS; ++c)
        sum += lpart[c * N + j] * __expf(mpart[c * N + j] - mx);
    m[j]  = mx;
    rl[j] = 1.0f / sum;
}

// ---------------- K3: out_part = exp(s - m) * (inputs * rl), split-K over j ----
__global__ __launch_bounds__(256) void k_agg(
    const float* __restrict__ s, const float* __restrict__ inputs,
    const float* __restrict__ m, const float* __restrict__ rl,
    float* __restrict__ part)
{
    __shared__ float bt[64 * D];        // 32 KB: inputs tile, pre-scaled by rl[j]
    __shared__ float at[64 * 65];       // 16.25 KB: exp tile, padded stride 65
    const int t  = threadIdx.x;
    const int i0 = (blockIdx.x & 31) * 64;
    const int sp = blockIdx.x >> 5;
    const int tr = t >> 4;              // rows tr*4 .. tr*4+3
    const int tc = t & 15;              // cols tc*8 .. tc*8+7
    float acc[4][8];
    #pragma unroll
    for (int a = 0; a < 4; ++a)
        #pragma unroll
        for (int b = 0; b < 8; ++b) acc[a][b] = 0.f;

    for (int tt = 0; tt < 4; ++tt) {
        const int j0 = sp * 256 + tt * 64;
        #pragma unroll
        for (int k = 0; k < 8; ++k) {
            int idx4 = k * 256 + t;
            int jj = idx4 >> 5, d4 = idx4 & 31;
            float4 v = *(const float4*)&inputs[(size_t)(j0 + jj) * D + d4 * 4];
            float sc = rl[j0 + jj];
            v.x *= sc; v.y *= sc; v.z *= sc; v.w *= sc;
            *(float4*)&bt[idx4 * 4] = v;
        }
        #pragma unroll
        for (int k = 0; k < 16; ++k) {
            int idx = k * 256 + t;
            int r = idx >> 6, jj = idx & 63;
            float sv = s[(size_t)(i0 + r) * N + j0 + jj];
            at[r * 65 + jj] = __expf(sv - m[j0 + jj]);
        }
        __syncthreads();
        for (int jj = 0; jj < 64; ++jj) {
            float4 x = *(float4*)&bt[jj * D + tc * 8];
            float4 y = *(float4*)&bt[jj * D + tc * 8 + 4];
            #pragma unroll
            for (int rr = 0; rr < 4; ++rr) {
                float a = at[(tr * 4 + rr) * 65 + jj];
                acc[rr][0] += a * x.x; acc[rr][1] += a * x.y;
                acc[rr][2] += a * x.z; acc[rr][3] += a * x.w;
                acc[rr][4] += a * y.x; acc[rr][5] += a * y.y;
                acc[rr][6] += a * y.z; acc[rr][7] += a * y.w;
            }
        }
        __syncthreads();
    }
    #pragma unroll
    for (int rr = 0; rr < 4; ++rr) {
        size_t o = ((size_t)sp * N + i0 + tr * 4 + rr) * D + tc * 8;
        *(float4*)&part[o]     = make_float4(acc[rr][0], acc[rr][1], acc[rr][2], acc[rr][3]);
        *(float4*)&part[o + 4] = make_float4(acc[rr][4], acc[rr][5], acc[rr][6], acc[rr][7]);
    }
}

// ---------------- K4: reduce SPLIT partials ----------------
__global__ __launch_bounds__(256) void k_reduce(
    const float* __restrict__ part, float* __restrict__ out)
{
    int idx = blockIdx.x * 256 + threadIdx.x;
    float4 v = make_float4(0.f, 0.f, 0.f, 0.f);
    #pragma unroll
    for (int sp = 0; sp < SPLIT; ++sp) {
        float4 p = *(const float4*)&part[(size_t)sp * N * D + (size_t)idx * 4];
        v.x += p.x; v.y += p.y; v.z += p.z; v.w += p.w;
    }
    *(float4*)&out[(size_t)idx * 4] = v;
}

extern "C" void kernel_launch(void* const* d_in, const int* in_sizes, int n_in,
                              void* d_out, int out_size, void* d_ws, size_t ws_size,
                              hipStream_t stream) {
    const float* inputs   = (const float*)d_in[0];
    const float* relation = (const float*)d_in[1];
    const float* rel_mask = (const float*)d_in[2];
    const float* w_rel    = (const float*)d_in[3];
    const float* b_rel    = (const float*)d_in[4];
    const float* w_head   = (const float*)d_in[5];
    const float* b_head   = (const float*)d_in[6];
    const float* w_tail   = (const float*)d_in[7];
    const float* b_tail   = (const float*)d_in[8];
    float* out = (float*)d_out;

    // ws (floats): s[N*N] | head[N] | tail[N] | m[N] | rl[N] | part[SPLIT*N*D]
    //            | mpart[CHUNKS*N] | lpart[CHUNKS*N]
    float* ws    = (float*)d_ws;
    float* s     = ws;
    float* head  = ws + (size_t)N * N;
    float* tail  = head + N;
    float* m     = tail + N;
    float* rl    = m + N;
    float* part  = rl + N;
    float* mpart = part + (size_t)SPLIT * N * D;
    float* lpart = mpart + (size_t)CHUNKS * N;

    k_headtail<<<N / 64, 256, 0, stream>>>(inputs, w_head, b_head, w_tail, b_tail, head, tail);
    k_scores<<<256, 256, 0, stream>>>(relation, rel_mask, w_rel, b_rel, head, tail, s);
    k_colstats_part<<<8 * CHUNKS, 256, 0, stream>>>(s, mpart, lpart);
    k_colstats_comb<<<N / 256, 256, 0, stream>>>(mpart, lpart, m, rl);
    k_agg<<<32 * SPLIT, 256, 0, stream>>>(s, inputs, m, rl, part);
    k_reduce<<<(N * D / 4) / 256, 256, 0, stream>>>(part, out);
}

// Round 19
// 976.604 us; speedup vs baseline: 1.0190x; 1.0190x over previous
//
#include <hip/hip_runtime.h>
#include <math.h>

#define N 2048
#define D 128
#define R 43
#define SPLIT 8
#define CHUNKS 32   // row-chunks for column-softmax stats

// ---------------- K0: head/tail vectors (4 lanes per row, float4) ----------------
__global__ __launch_bounds__(256) void k_headtail(
    const float* __restrict__ inputs,
    const float* __restrict__ w_head, const float* __restrict__ b_head,
    const float* __restrict__ w_tail, const float* __restrict__ b_tail,
    float* __restrict__ head, float* __restrict__ tail)
{
    const int t = threadIdx.x;
    const int row = blockIdx.x * 64 + (t >> 2);
    const int q = t & 3;                       // quarter of the row (32 floats)
    const float4* rp = (const float4*)(inputs + (size_t)row * D + q * 32);
    const float4* wh = (const float4*)(w_head + q * 32);
    const float4* wt = (const float4*)(w_tail + q * 32);
    float h = 0.f, tl = 0.f;
    #pragma unroll
    for (int k = 0; k < 8; ++k) {
        float4 v = rp[k];
        float4 a = wh[k];
        float4 b = wt[k];
        h  += v.x * a.x + v.y * a.y + v.z * a.z + v.w * a.w;
        tl += v.x * b.x + v.y * b.y + v.z * b.z + v.w * b.w;
    }
    h  += __shfl_xor(h, 1);  h  += __shfl_xor(h, 2);
    tl += __shfl_xor(tl, 1); tl += __shfl_xor(tl, 2);
    if (q == 0) {
        head[row] = h  + b_head[0];
        tail[row] = tl + b_tail[0];
    }
}

// ---------------- K1: s[i][j] = rel(i,j,:)*w + b + head[i] + tail[j] + mask ----
// Barrier-free register-staged streaming (design #3; T14 pattern).
// Each WAVE privately handles one 64-pair chunk = 11008 contiguous bytes:
//   coalesced loads -> regs -> ds_write to wave-private slab -> stride-43 dot.
// No __syncthreads, no global_load_lds: 44 KB LDS/block -> 3 blocks/CU ->
// 12 fully independent waves/CU; HBM latency hidden by TLP, never drained
// by a block-wide barrier. Read alias (43 mod 32 = 11, gcd 1) = 2-way, free.
__global__ __launch_bounds__(256) void k_scores(
    const float* __restrict__ rel, const float* __restrict__ rel_mask,
    const float* __restrict__ w_rel, const float* __restrict__ b_rel,
    const float* __restrict__ head, const float* __restrict__ tail,
    float* __restrict__ s)
{
    __shared__ float lds[4 * 2752];            // 4 waves x 11008 B = 44032 B
    const int t    = threadIdx.x;
    const int lane = t & 63;
    const int wave = t >> 6;

    // rel-weight vector: uniform
    float w[R];
    #pragma unroll
    for (int r = 0; r < R; ++r) w[r] = w_rel[r];
    const float brel = b_rel[0];

    const size_t pair0 = (size_t)blockIdx.x * 256 + wave * 64;  // wave's 64 pairs
    const char*  src   = (const char*)rel + pair0 * 172;        // 11008-B aligned
    char*        sb    = (char*)(lds + wave * 2752);            // wave-private slab

    // stage 11008 B: 10 x b128 coalesced + 3 x b32 coalesced, via registers
    float4 v[10];
    float  x[3];
    #pragma unroll
    for (int k = 0; k < 10; ++k)
        v[k] = *(const float4*)(src + k * 1024 + lane * 16);
    #pragma unroll
    for (int k = 0; k < 3; ++k)
        x[k] = *(const float*)(src + 10240 + k * 256 + lane * 4);
    #pragma unroll
    for (int k = 0; k < 10; ++k)
        *(float4*)(sb + k * 1024 + lane * 16) = v[k];
    #pragma unroll
    for (int k = 0; k < 3; ++k)
        *(float*)(sb + 10240 + k * 256 + lane * 4) = x[k];
    // compiler inserts lgkmcnt wait before dependent ds_read (same wave, in order)

    const size_t p = pair0 + lane;
    const int i = (int)(p >> 11);              // uniform within the wave
    const int j = (int)(p & (N - 1));
    const float hd = head[i];
    const float tl = tail[j];
    const float mk = rel_mask[p];

    const float* b = (const float*)sb + lane * 43;
    float a0 = 0.f, a1 = 0.f, a2 = 0.f, a3 = 0.f;
    #pragma unroll
    for (int r = 0; r < 40; r += 4) {
        a0 += b[r]     * w[r];
        a1 += b[r + 1] * w[r + 1];
        a2 += b[r + 2] * w[r + 2];
        a3 += b[r + 3] * w[r + 3];
    }
    a0 += b[40] * w[40];
    a1 += b[41] * w[41];
    a2 += b[42] * w[42];

    s[p] = brel + ((a0 + a1) + (a2 + a3)) + hd + tl + mk;
}

// ---------------- K2a: per-column partial (max, sumexp) over a 64-row chunk ----
__global__ __launch_bounds__(256) void k_colstats_part(
    const float* __restrict__ s, float* __restrict__ mpart, float* __restrict__ lpart)
{
    const int j = (blockIdx.x & 7) * 256 + threadIdx.x;   // column, coalesced
    const int c = blockIdx.x >> 3;                        // row chunk 0..31
    const int i0 = c * 64;
    float mx = -1e30f;
    for (int i = i0; i < i0 + 64; ++i)
        mx = fmaxf(mx, s[(size_t)i * N + j]);
    float sum = 0.f;
    for (int i = i0; i < i0 + 64; ++i)
        sum += __expf(s[(size_t)i * N + j] - mx);         // 2nd pass: L1/L2 hits
    mpart[c * N + j] = mx;
    lpart[c * N + j] = sum;
}

// ---------------- K2b: combine 32 chunk partials -> m, 1/l ----------------
__global__ __launch_bounds__(256) void k_colstats_comb(
    const float* __restrict__ mpart, const float* __restrict__ lpart,
    float* __restrict__ m, float* __restrict__ rl)
{
    const int j = blockIdx.x * 256 + threadIdx.x;
    float mx = -1e30f;
    #pragma unroll 8
    for (int c = 0; c < CHUNKS; ++c)
        mx = fmaxf(mx, mpart[c * N + j]);
    float sum = 0.f;
    #pragma unroll 8
    for (int c = 0; c < CHUNKS; ++c)
        sum += lpart[c * N + j] * __expf(mpart[c * N + j] - mx);
    m[j]  = mx;
    rl[j] = 1.0f / sum;
}

// ---------------- K3: out_part = exp(s - m) * (inputs * rl), split-K over j ----
__global__ __launch_bounds__(256) void k_agg(
    const float* __restrict__ s, const float* __restrict__ inputs,
    const float* __restrict__ m, const float* __restrict__ rl,
    float* __restrict__ part)
{
    __shared__ float bt[64 * D];        // 32 KB: inputs tile, pre-scaled by rl[j]
    __shared__ float at[64 * 65];       // 16.25 KB: exp tile, padded stride 65
    const int t  = threadIdx.x;
    const int i0 = (blockIdx.x & 31) * 64;
    const int sp = blockIdx.x >> 5;
    const int tr = t >> 4;              // rows tr*4 .. tr*4+3
    const int tc = t & 15;              // cols tc*8 .. tc*8+7
    float acc[4][8];
    #pragma unroll
    for (int a = 0; a < 4; ++a)
        #pragma unroll
        for (int b = 0; b < 8; ++b) acc[a][b] = 0.f;

    for (int tt = 0; tt < 4; ++tt) {
        const int j0 = sp * 256 + tt * 64;
        #pragma unroll
        for (int k = 0; k < 8; ++k) {
            int idx4 = k * 256 + t;
            int jj = idx4 >> 5, d4 = idx4 & 31;
            float4 v = *(const float4*)&inputs[(size_t)(j0 + jj) * D + d4 * 4];
            float sc = rl[j0 + jj];
            v.x *= sc; v.y *= sc; v.z *= sc; v.w *= sc;
            *(float4*)&bt[idx4 * 4] = v;
        }
        #pragma unroll
        for (int k = 0; k < 16; ++k) {
            int idx = k * 256 + t;
            int r = idx >> 6, jj = idx & 63;
            float sv = s[(size_t)(i0 + r) * N + j0 + jj];
            at[r * 65 + jj] = __expf(sv - m[j0 + jj]);
        }
        __syncthreads();
        for (int jj = 0; jj < 64; ++jj) {
            float4 x = *(float4*)&bt[jj * D + tc * 8];
            float4 y = *(float4*)&bt[jj * D + tc * 8 + 4];
            #pragma unroll
            for (int rr = 0; rr < 4; ++rr) {
                float a = at[(tr * 4 + rr) * 65 + jj];
                acc[rr][0] += a * x.x; acc[rr][1] += a * x.y;
                acc[rr][2] += a * x.z; acc[rr][3] += a * x.w;
                acc[rr][4] += a * y.x; acc[rr][5] += a * y.y;
                acc[rr][6] += a * y.z; acc[rr][7] += a * y.w;
            }
        }
        __syncthreads();
    }
    #pragma unroll
    for (int rr = 0; rr < 4; ++rr) {
        size_t o = ((size_t)sp * N + i0 + tr * 4 + rr) * D + tc * 8;
        *(float4*)&part[o]     = make_float4(acc[rr][0], acc[rr][1], acc[rr][2], acc[rr][3]);
        *(float4*)&part[o + 4] = make_float4(acc[rr][4], acc[rr][5], acc[rr][6], acc[rr][7]);
    }
}

// ---------------- K4: reduce SPLIT partials ----------------
__global__ __launch_bounds__(256) void k_reduce(
    const float* __restrict__ part, float* __restrict__ out)
{
    int idx = blockIdx.x * 256 + threadIdx.x;
    float4 v = make_float4(0.f, 0.f, 0.f, 0.f);
    #pragma unroll
    for (int sp = 0; sp < SPLIT; ++sp) {
        float4 p = *(const float4*)&part[(size_t)sp * N * D + (size_t)idx * 4];
        v.x += p.x; v.y += p.y; v.z += p.z; v.w += p.w;
    }
    *(float4*)&out[(size_t)idx * 4] = v;
}

extern "C" void kernel_launch(void* const* d_in, const int* in_sizes, int n_in,
                              void* d_out, int out_size, void* d_ws, size_t ws_size,
                              hipStream_t stream) {
    const float* inputs   = (const float*)d_in[0];
    const float* relation = (const float*)d_in[1];
    const float* rel_mask = (const float*)d_in[2];
    const float* w_rel    = (const float*)d_in[3];
    const float* b_rel    = (const float*)d_in[4];
    const float* w_head   = (const float*)d_in[5];
    const float* b_head   = (const float*)d_in[6];
    const float* w_tail   = (const float*)d_in[7];
    const float* b_tail   = (const float*)d_in[8];
    float* out = (float*)d_out;

    // ws (floats): s[N*N] | head[N] | tail[N] | m[N] | rl[N] | part[SPLIT*N*D]
    //            | mpart[CHUNKS*N] | lpart[CHUNKS*N]
    float* ws    = (float*)d_ws;
    float* s     = ws;
    float* head  = ws + (size_t)N * N;
    float* tail  = head + N;
    float* m     = tail + N;
    float* rl    = m + N;
    float* part  = rl + N;
    float* mpart = part + (size_t)SPLIT * N * D;
    float* lpart = mpart + (size_t)CHUNKS * N;

    k_headtail<<<N / 64, 256, 0, stream>>>(inputs, w_head, b_head, w_tail, b_tail, head, tail);
    k_scores<<<(N * N) / 256, 256, 0, stream>>>(relation, rel_mask, w_rel, b_rel, head, tail, s);
    k_colstats_part<<<8 * CHUNKS, 256, 0, stream>>>(s, mpart, lpart);
    k_colstats_comb<<<N / 256, 256, 0, stream>>>(mpart, lpart, m, rl);
    k_agg<<<32 * SPLIT, 256, 0, stream>>>(s, inputs, m, rl, part);
    k_reduce<<<(N * D / 4) / 256, 256, 0, stream>>>(part, out);
}